// Round 4
// baseline (200.054 us; speedup 1.0000x reference)
//
#include <hip/hip_runtime.h>

// Problem constants (from reference)
#define D0 256
#define D1 256
#define D2 256
#define NPTS 65536
#define WIN 7
#define HALF 3

#define NWAVES 8192              // 2048 blocks x 4 waves
#define PTS_PER_WAVE (NPTS / NWAVES)   // 8

// ---------------------------------------------------------------------------
// Compile-time table of feasible window offsets.
// dx = (floor(px)-3+oi) - px  =>  dx in (oi-4, oi-3], so min dx^2 per axis is
// m = [9,4,1,0,0,1,4]. Offset (i,j,k) can only pass dist2<=9 if
// m[i]+m[j]+m[k] <= 9  ->  220 of 343 offsets. Pad to 256 with (100,100,100)
// which always fails dist2<=9, so no special-casing needed.
// ---------------------------------------------------------------------------
struct OffTable { unsigned v[256]; };

constexpr OffTable make_table() {
    OffTable t{};
    int m[7] = {9, 4, 1, 0, 0, 1, 4};
    int n = 0;
    for (int i = 0; i < 7; i++)
        for (int j = 0; j < 7; j++)
            for (int k = 0; k < 7; k++)
                if (m[i] + m[j] + m[k] <= 9)
                    t.v[n++] = (unsigned)(i | (j << 8) | (k << 16));
    for (; n < 256; n++)
        t.v[n] = (unsigned)(100 | (100 << 8) | (100 << 16));
    return t;
}

__device__ __constant__ OffTable g_tab = make_table();

__global__ __launch_bounds__(256)
void splat_kernel(const float* __restrict__ paras,
                  const float* __restrict__ dist_p,
                  const float* __restrict__ thr_p,
                  float* __restrict__ out) {
    int wid  = (blockIdx.x * blockDim.x + threadIdx.x) >> 6;
    int lane = threadIdx.x & 63;

    // Per-lane offset table, decoded ONCE per wave (registers only in hot loop).
    int   oi[4], oj[4], ok[4];
    float foi[4], foj[4], fok[4];
#pragma unroll
    for (int t = 0; t < 4; t++) {
        unsigned pk = g_tab.v[t * 64 + lane];
        oi[t] = pk & 255;
        oj[t] = (pk >> 8) & 255;
        ok[t] = pk >> 16;
        foi[t] = (float)oi[t];
        foj[t] = (float)oj[t];
        fok[t] = (float)ok[t];
    }

    float dist  = dist_p[0];
    float thr   = thr_p[0];
    float d2max = dist * dist;

    const int N = NPTS;
    int p = __builtin_amdgcn_readfirstlane(wid);

    // Load first point's params.
    float px  = paras[0 * N + p], py  = paras[1 * N + p], pz  = paras[2 * N + p];
    float val = paras[3 * N + p];
    float rx  = paras[4 * N + p], rxy = paras[5 * N + p], rxz = paras[6 * N + p];
    float ry  = paras[7 * N + p], ryz = paras[8 * N + p], rz  = paras[9 * N + p];

    for (int it = 0; it < PTS_PER_WAVE; it++) {
        // Prefetch next point's params (scalar loads issue now; waited on at
        // first use next iteration -> latency hidden under this point's work).
        float npx = 0, npy = 0, npz = 0, nval = 0, nrx = 1, nrxy = 0, nrxz = 0,
              nry = 1, nryz = 0, nrz = 1;
        if (it + 1 < PTS_PER_WAVE) {
            int pn = __builtin_amdgcn_readfirstlane(p + NWAVES);
            npx  = paras[0 * N + pn]; npy  = paras[1 * N + pn]; npz = paras[2 * N + pn];
            nval = paras[3 * N + pn];
            nrx  = paras[4 * N + pn]; nrxy = paras[5 * N + pn]; nrxz = paras[6 * N + pn];
            nry  = paras[7 * N + pn]; nryz = paras[8 * N + pn]; nrz  = paras[9 * N + pn];
        }

        int cx = (int)floorf(px) - HALF;
        int cy = (int)floorf(py) - HALF;
        int cz = (int)floorf(pz) - HALF;
        float fx = (float)cx - px;       // dx = fx + oi
        float fy = (float)cy - py;
        float fz = (float)cz - pz;

        float irx = __fdividef(1.0f, rx);
        float iry = __fdividef(1.0f, ry);
        float irz = __fdividef(1.0f, rz);

#pragma unroll
        for (int t = 0; t < 4; t++) {
            int vx = cx + oi[t];
            int vy = cy + oj[t];
            int vz = cz + ok[t];

            float dx = fx + foi[t];
            float dy = fy + foj[t];
            float dz = fz + fok[t];
            float d2 = dx * dx + dy * dy + dz * dz;

            bool inb = ((unsigned)vx < (unsigned)D0) &
                       ((unsigned)vy < (unsigned)D1) &
                       ((unsigned)vz < (unsigned)D2);

            if (inb && d2 <= d2max) {
                float ax = dx * irx, ay = dy * iry, az = dz * irz;
                float q = ax * ax + ay * ay + az * az
                        + rxy * dx * dy + rxz * dx * dz + ryz * dy * dz;
                float w = __expf(-0.5f * q);
                if (w > thr) {
                    int flat = (vx << 16) + (vy << 8) + vz;
                    atomicAdd(&out[flat], val * w);
                }
            }
        }

        // Rotate in the prefetched params.
        px = npx; py = npy; pz = npz; val = nval;
        rx = nrx; rxy = nrxy; rxz = nrxz; ry = nry; ryz = nryz; rz = nrz;
        p += NWAVES;
    }
}

__global__ __launch_bounds__(256)
void zero_kernel(float4* __restrict__ out, int n4) {
    int i = blockIdx.x * blockDim.x + threadIdx.x;
    int stride = gridDim.x * blockDim.x;
    for (; i < n4; i += stride)
        out[i] = make_float4(0.f, 0.f, 0.f, 0.f);
}

extern "C" void kernel_launch(void* const* d_in, const int* in_sizes, int n_in,
                              void* d_out, int out_size, void* d_ws, size_t ws_size,
                              hipStream_t stream) {
    const float* paras  = (const float*)d_in[0];
    const float* dist_p = (const float*)d_in[1];
    const float* thr_p  = (const float*)d_in[2];
    float* out = (float*)d_out;

    // Output is re-poisoned (0xAA) before every timed launch; zero it.
    int n4 = out_size / 4;
    zero_kernel<<<4096, 256, 0, stream>>>((float4*)out, n4);

    // 2048 blocks x 4 waves = 8192 waves; each wave handles 8 points.
    splat_kernel<<<2048, 256, 0, stream>>>(paras, dist_p, thr_p, out);
}